// Round 1
// baseline (255.061 us; speedup 1.0000x reference)
//
#include <hip/hip_runtime.h>
#include <cstdint>

#define BATCH 8
#define CIN 64
#define COUT 128
#define HH 32
#define WW 32
// output [B, COUT, 32, 32] fp32, 1,048,576 elems

// ---------------- workspace layout ----------------
// u32[0] : absmax_x bits
// u32[1] : absmax_w bits
// f32[2] : Tf
// f32[3] : Tw
// byte 64           : xq int8 [B*CIN*H*W]  = 524288 B
// byte 64+524288    : wq int8 [COUT*CIN*9] =  73728 B

__global__ void init_kernel(unsigned* ws_u32) {
    if (threadIdx.x < 2) ws_u32[threadIdx.x] = 0u;
}

__global__ void absmax_kernel(const float* __restrict__ p, int n, unsigned* __restrict__ tgt) {
    unsigned m = 0;
    for (int i = blockIdx.x * blockDim.x + threadIdx.x; i < n; i += gridDim.x * blockDim.x) {
        unsigned b = __float_as_uint(p[i]) & 0x7fffffffu;
        m = m > b ? m : b;
    }
    // wave-64 butterfly reduce
    #pragma unroll
    for (int off = 32; off > 0; off >>= 1) {
        unsigned o = (unsigned)__shfl_xor((int)m, off, 64);
        m = m > o ? m : o;
    }
    if ((threadIdx.x & 63) == 0) atomicMax(tgt, m);
}

__global__ void quantize_kernel(const float* __restrict__ p, int n, int8_t* __restrict__ q,
                                const unsigned* __restrict__ absbits,
                                const float* __restrict__ T_in, float* __restrict__ T_out) {
    float amax = __uint_as_float(*absbits);
    // match reference op order: 0.95*T + 0.05*amax (separate mul/add, fp32)
    float a = 0.95f * T_in[0];
    float b = 0.05f * amax;
    float T = a + b;
    if (blockIdx.x == 0 && threadIdx.x == 0) *T_out = T;
    float scale = 127.0f / T;  // exact fp32 division, as jnp
    for (int i = blockIdx.x * blockDim.x + threadIdx.x; i < n; i += gridDim.x * blockDim.x) {
        float v = p[i] * scale;
        v = rintf(v);                         // nearest-even == jnp.round
        v = fminf(fmaxf(v, -128.0f), 127.0f); // clip after round, as reference
        q[i] = (int8_t)(int)v;
    }
}

__global__ __launch_bounds__(256) void conv_kernel(const int8_t* __restrict__ xq,
                                                   const int8_t* __restrict__ wq,
                                                   const float* __restrict__ bias,
                                                   const float* __restrict__ Tf_p,
                                                   const float* __restrict__ Tw_p,
                                                   float* __restrict__ out) {
    // flat = ((b*COUT + co)*1024 + oh*32 + ow); one block = 256 outputs, uniform (b,co)
    int flat = blockIdx.x * 256 + threadIdx.x;
    int ow = flat & 31;
    int oh = (flat >> 5) & 31;
    int co = (flat >> 10) & (COUT - 1);
    int b  = flat >> 17;

    // stage this co's 576 weights in LDS (sign-extended to int); reads broadcast
    __shared__ int wsm[CIN * 9];
    const int8_t* wrow = wq + co * CIN * 9;
    for (int t = threadIdx.x; t < CIN * 9; t += 256) wsm[t] = (int)wrow[t];
    __syncthreads();

    int acc = 0;
    const int8_t* xb = xq + b * CIN * HH * WW;
    for (int ci = 0; ci < CIN; ++ci) {
        const int8_t* xc = xb + ci * HH * WW;
        const int* wc = wsm + ci * 9;
        #pragma unroll
        for (int kh = 0; kh < 3; ++kh) {
            int ih = oh + kh - 1;
            if (ih < 0 || ih >= HH) continue;
            const int8_t* xr = xc + ih * WW;
            #pragma unroll
            for (int kw = 0; kw < 3; ++kw) {
                int iw = ow + kw - 1;
                if (iw < 0 || iw >= WW) continue;
                acc += (int)xr[iw] * wc[kh * 3 + kw];
            }
        }
    }

    float Tf = *Tf_p;
    float Tw = *Tw_p;
    float s = (Tf / 127.0f) * (Tw / 127.0f);  // exact fp32 divisions, as reference
    out[flat] = (float)acc * s + bias[co];
}

extern "C" void kernel_launch(void* const* d_in, const int* in_sizes, int n_in,
                              void* d_out, int out_size, void* d_ws, size_t ws_size,
                              hipStream_t stream) {
    const float* x        = (const float*)d_in[0];  // [8,64,32,32]
    const float* weight   = (const float*)d_in[1];  // [128,64,3,3]
    const float* bias     = (const float*)d_in[2];  // [128]
    // d_in[3] = lut (exact a*b table -> replaced by integer multiply)
    // d_in[4] = gradient_lut (unused in forward)
    const float* T_feature = (const float*)d_in[5];
    const float* T_weight  = (const float*)d_in[6];

    unsigned* ws_u32 = (unsigned*)d_ws;
    float*    ws_f32 = (float*)d_ws;
    int8_t*   xq = (int8_t*)d_ws + 64;
    int8_t*   wq = (int8_t*)d_ws + 64 + BATCH * CIN * HH * WW;

    const int nx = BATCH * CIN * HH * WW;   // 524288
    const int nw = COUT * CIN * 9;          // 73728

    init_kernel<<<1, 64, 0, stream>>>(ws_u32);

    absmax_kernel<<<1024, 256, 0, stream>>>(x, nx, &ws_u32[0]);
    absmax_kernel<<<288, 256, 0, stream>>>(weight, nw, &ws_u32[1]);

    quantize_kernel<<<(nx + 255) / 256, 256, 0, stream>>>(x, nx, xq, &ws_u32[0], T_feature, &ws_f32[2]);
    quantize_kernel<<<(nw + 255) / 256, 256, 0, stream>>>(weight, nw, wq, &ws_u32[1], T_weight, &ws_f32[3]);

    conv_kernel<<<(BATCH * COUT * HH * WW) / 256, 256, 0, stream>>>(
        xq, wq, bias, &ws_f32[2], &ws_f32[3], (float*)d_out);
}

// Round 2
// 76.374 us; speedup vs baseline: 3.3396x; 3.3396x over previous
//
#include <hip/hip_runtime.h>
#include <cstdint>

#define BATCH 8
#define CIN 64
#define COUT 128
#define HH 32
#define WW 32
#define PH 34   // padded H
#define PW 34   // padded W

typedef int v4i __attribute__((ext_vector_type(4)));

// ---------------- workspace layout ----------------
// f32[0..255]  @ byte 0    : reserved scalars (we use [2]=Tf, [3]=Tw... see below)
//   actually: partials live at f32[16..175]; Tf at f32[0], Tw at f32[1]
// byte 4096              : xpad  int8 NHWC-padded [8,34,34,64] = 591872 B
// byte 4096+591872=595968: wfrag int8 MFMA-B-swizzled [9][8][64][16] = 73728 B
#define WS_TF 0
#define WS_TW 1
#define WS_PART 16      // partials: x at [16..143], w at [144..159]
#define XPAD_OFF 4096
#define WFRAG_OFF (4096 + BATCH * PH * PW * CIN)

// ---------- kernel 1: per-block absmax partials (no atomics, no init) ----------
__global__ __launch_bounds__(256) void absmax_partial(const float* __restrict__ x,
                                                      const float* __restrict__ w,
                                                      float* __restrict__ partials) {
    float m = 0.0f;
    if (blockIdx.x < 128) {
        // x: 524288 floats = 131072 float4; 1024 float4/block, 4 iters
        const float4* p = (const float4*)x;
        int base = blockIdx.x * 1024 + threadIdx.x;
        #pragma unroll
        for (int k = 0; k < 4; ++k) {
            float4 v = p[base + k * 256];
            m = fmaxf(m, fmaxf(fmaxf(fabsf(v.x), fabsf(v.y)), fmaxf(fabsf(v.z), fabsf(v.w))));
        }
    } else {
        // w: 73728 floats = 18432 float4; 1152 float4/block over 16 blocks
        const float4* p = (const float4*)w;
        int wb = blockIdx.x - 128;
        int base = wb * 1152 + threadIdx.x;
        int end = (wb + 1) * 1152;
        #pragma unroll
        for (int k = 0; k < 5; ++k) {
            int i = base + k * 256;
            if (i < end) {
                float4 v = p[i];
                m = fmaxf(m, fmaxf(fmaxf(fabsf(v.x), fabsf(v.y)), fmaxf(fabsf(v.z), fabsf(v.w))));
            }
        }
    }
    // wave butterfly
    #pragma unroll
    for (int off = 32; off > 0; off >>= 1)
        m = fmaxf(m, __shfl_xor(m, off, 64));
    __shared__ float sm[4];
    int wave = threadIdx.x >> 6;
    if ((threadIdx.x & 63) == 0) sm[wave] = m;
    __syncthreads();
    if (threadIdx.x == 0)
        partials[WS_PART + blockIdx.x] = fmaxf(fmaxf(sm[0], sm[1]), fmaxf(sm[2], sm[3]));
}

__device__ __forceinline__ int quant1(float v, float scale) {
    float q = rintf(v * scale);
    q = fminf(fmaxf(q, -128.0f), 127.0f);
    return (int)q;
}

// ---------- kernel 2: fused quantize -> padded NHWC x + MFMA-swizzled w ----------
#define NBX 578  // x blocks: 8*34*34*64/4/256
#define NBW 72   // w blocks: 128*64*9/4/256
__global__ __launch_bounds__(256) void quant_pack(const float* __restrict__ x,
                                                  const float* __restrict__ w,
                                                  const float* __restrict__ Tf_in,
                                                  const float* __restrict__ Tw_in,
                                                  float* __restrict__ ws_f32,
                                                  uint8_t* __restrict__ xpad,
                                                  uint8_t* __restrict__ wfrag) {
    int lane = threadIdx.x & 63;
    if (blockIdx.x < NBX) {
        // ---- x branch: reduce 128 partials, quantize into padded NHWC ----
        float m = fmaxf(ws_f32[WS_PART + lane], ws_f32[WS_PART + 64 + lane]);
        #pragma unroll
        for (int off = 32; off > 0; off >>= 1)
            m = fmaxf(m, __shfl_xor(m, off, 64));
        float a = 0.95f * Tf_in[0];
        float b = 0.05f * m;
        float Tf = a + b;
        if (blockIdx.x == 0 && threadIdx.x == 0) ws_f32[WS_TF] = Tf;
        float scale = 127.0f / Tf;

        int tid = blockIdx.x * 256 + threadIdx.x;      // one uint (4 channels) each
        int idx4 = tid * 4;
        int ci0 = idx4 & 63;
        int rest = idx4 >> 6;                           // b*34*34 + ih*34 + iw
        int iw = rest % PW;
        int t2 = rest / PW;
        int ih = t2 % PH;
        int bb = t2 / PH;
        unsigned pack = 0;
        if (ih >= 1 && ih <= HH && iw >= 1 && iw <= WW) {
            int h = ih - 1, ww_ = iw - 1;
            #pragma unroll
            for (int c = 0; c < 4; ++c) {
                float v = x[((bb * CIN + ci0 + c) * HH + h) * WW + ww_];
                int q = quant1(v, scale);
                pack |= ((unsigned)(q & 255)) << (8 * c);
            }
        }
        ((unsigned*)xpad)[tid] = pack;
    } else {
        // ---- w branch: reduce 16 partials, quantize into MFMA-B fragment order ----
        float m = ws_f32[WS_PART + 128 + (lane & 15)];
        #pragma unroll
        for (int off = 32; off > 0; off >>= 1)
            m = fmaxf(m, __shfl_xor(m, off, 64));
        float a = 0.95f * Tw_in[0];
        float b = 0.05f * m;
        float Tw = a + b;
        if (blockIdx.x == NBX && threadIdx.x == 0) ws_f32[WS_TW] = Tw;
        float scale = 127.0f / Tw;

        int tid = (blockIdx.x - NBX) * 256 + threadIdx.x;  // one uint (4 k-bytes) each
        int idx4 = tid * 4;
        int j0 = idx4 & 15;            // byte within lane's 16
        int ln = (idx4 >> 4) & 63;     // fragment lane
        int f  = idx4 >> 10;           // fragment index = t*8 + nt8
        int nt8 = f & 7;
        int t = f >> 3;                // tap = kh*3+kw
        int kh = t / 3;
        int kw = t - kh * 3;
        int co = nt8 * 16 + (ln & 15);
        int ci0 = (ln >> 4) * 16 + j0;
        unsigned pack = 0;
        #pragma unroll
        for (int c = 0; c < 4; ++c) {
            float v = w[((co * CIN + ci0 + c) * 3 + kh) * 3 + kw];
            int q = quant1(v, scale);
            pack |= ((unsigned)(q & 255)) << (8 * c);
        }
        ((unsigned*)wfrag)[tid] = pack;
    }
}

// ---------- kernel 3: implicit-GEMM conv via mfma_i32_16x16x64_i8 ----------
// Block = 4 waves = tile M=32 pixels (one (b,oh) row) x N=128 couts.
// wave w: mt = w&1 (pixel half), nh = w>>1 (cout half of 64).
__global__ __launch_bounds__(256) void conv_mfma(const uint8_t* __restrict__ xpad,
                                                 const uint8_t* __restrict__ wfrag,
                                                 const float* __restrict__ bias,
                                                 const float* __restrict__ ws_f32,
                                                 float* __restrict__ out) {
    int mb = blockIdx.x;          // 256 tiles: b = mb>>5, oh = mb&31
    int b = mb >> 5;
    int oh = mb & 31;
    int wave = threadIdx.x >> 6;
    int lane = threadIdx.x & 63;
    int mt = wave & 1;
    int nh = wave >> 1;
    int row = lane & 15;          // A: m-row; B: n-col; C: n-col
    int quad = lane >> 4;

    v4i acc[4];
    #pragma unroll
    for (int nt = 0; nt < 4; ++nt) acc[nt] = (v4i){0, 0, 0, 0};

    // A base: pixel (b, oh+kh, mt*16+row+kw) channels quad*16..+15
    const uint8_t* xbase = xpad + (((b * PH + oh) * PW) + mt * 16 + row) * CIN + quad * 16;

    #pragma unroll
    for (int t = 0; t < 9; ++t) {
        const int kh = t / 3, kw = t % 3;
        v4i afrag = *(const v4i*)(xbase + (kh * PW + kw) * CIN);
        #pragma unroll
        for (int nt = 0; nt < 4; ++nt) {
            v4i bfrag = *(const v4i*)(wfrag + (((t * 8 + nh * 4 + nt) * 64) + lane) * 16);
            acc[nt] = __builtin_amdgcn_mfma_i32_16x16x64_i8(afrag, bfrag, acc[nt], 0, 0, 0);
        }
    }

    float Tf = ws_f32[WS_TF];
    float Tw = ws_f32[WS_TW];
    float s = (Tf / 127.0f) * (Tw / 127.0f);
    int ow0 = mt * 16 + quad * 4;
    #pragma unroll
    for (int nt = 0; nt < 4; ++nt) {
        int co = nh * 64 + nt * 16 + row;
        float bb = bias[co];
        float4 o;
        o.x = (float)acc[nt][0] * s + bb;
        o.y = (float)acc[nt][1] * s + bb;
        o.z = (float)acc[nt][2] * s + bb;
        o.w = (float)acc[nt][3] * s + bb;
        *(float4*)(out + (((b * COUT + co) * HH + oh) * WW) + ow0) = o;
    }
}

extern "C" void kernel_launch(void* const* d_in, const int* in_sizes, int n_in,
                              void* d_out, int out_size, void* d_ws, size_t ws_size,
                              hipStream_t stream) {
    const float* x        = (const float*)d_in[0];  // [8,64,32,32]
    const float* weight   = (const float*)d_in[1];  // [128,64,3,3]
    const float* bias     = (const float*)d_in[2];  // [128]
    // d_in[3]=lut (exact a*b), d_in[4]=gradient_lut: unused
    const float* T_feature = (const float*)d_in[5];
    const float* T_weight  = (const float*)d_in[6];

    float*   ws_f32 = (float*)d_ws;
    uint8_t* xpad   = (uint8_t*)d_ws + XPAD_OFF;
    uint8_t* wfrag  = (uint8_t*)d_ws + WFRAG_OFF;

    absmax_partial<<<144, 256, 0, stream>>>(x, weight, ws_f32);
    quant_pack<<<NBX + NBW, 256, 0, stream>>>(x, weight, T_feature, T_weight,
                                              ws_f32, xpad, wfrag);
    conv_mfma<<<256, 256, 0, stream>>>(xpad, wfrag, bias, ws_f32, (float*)d_out);
}

// Round 3
// 75.004 us; speedup vs baseline: 3.4006x; 1.0183x over previous
//
#include <hip/hip_runtime.h>
#include <cstdint>

#define BATCH 8
#define CIN 64
#define COUT 128
#define HH 32
#define WW 32
#define PH 34   // padded H
#define PW 34   // padded W

typedef int v4i __attribute__((ext_vector_type(4)));

// ---------------- workspace layout ----------------
// f32[0] Tf, f32[1] Tw, f32[16..175] partials (x: 16..143, w: 144..159)
// byte 4096   : xpad  int8 NHWC-padded [8,34,34,64] = 591872 B
// byte 595968 : wfrag int8 MFMA-B-swizzled [9][8][64][16] = 73728 B
#define WS_TF 0
#define WS_TW 1
#define WS_PART 16
#define XPAD_OFF 4096
#define WFRAG_OFF (4096 + BATCH * PH * PW * CIN)

// ---------- kernel 1: per-block absmax partials ----------
__global__ __launch_bounds__(256) void absmax_partial(const float* __restrict__ x,
                                                      const float* __restrict__ w,
                                                      float* __restrict__ partials) {
    float m = 0.0f;
    if (blockIdx.x < 128) {
        const float4* p = (const float4*)x;
        int base = blockIdx.x * 1024 + threadIdx.x;
        #pragma unroll
        for (int k = 0; k < 4; ++k) {
            float4 v = p[base + k * 256];
            m = fmaxf(m, fmaxf(fmaxf(fabsf(v.x), fabsf(v.y)), fmaxf(fabsf(v.z), fabsf(v.w))));
        }
    } else {
        const float4* p = (const float4*)w;
        int wb = blockIdx.x - 128;
        int base = wb * 1152 + threadIdx.x;
        int end = (wb + 1) * 1152;
        #pragma unroll
        for (int k = 0; k < 5; ++k) {
            int i = base + k * 256;
            if (i < end) {
                float4 v = p[i];
                m = fmaxf(m, fmaxf(fmaxf(fabsf(v.x), fabsf(v.y)), fmaxf(fabsf(v.z), fabsf(v.w))));
            }
        }
    }
    #pragma unroll
    for (int off = 32; off > 0; off >>= 1)
        m = fmaxf(m, __shfl_xor(m, off, 64));
    __shared__ float sm[4];
    int wave = threadIdx.x >> 6;
    if ((threadIdx.x & 63) == 0) sm[wave] = m;
    __syncthreads();
    if (threadIdx.x == 0)
        partials[WS_PART + blockIdx.x] = fmaxf(fmaxf(sm[0], sm[1]), fmaxf(sm[2], sm[3]));
}

__device__ __forceinline__ unsigned quantb(float v, float scale) {
    float q = rintf(v * scale);
    q = fminf(fmaxf(q, -128.0f), 127.0f);
    return ((unsigned)(int)q) & 255u;
}

// ---------- kernel 2: fused quantize+pack ----------
// blocks [0,256)   : x rows -> coalesced read, LDS transpose, NHWC write
// blocks [256,328) : weights -> MFMA-B fragment order
// blocks [328,394) : xpad border zero-fill
#define QB_X 256
#define QB_W 72
#define QB_Z 66
__global__ __launch_bounds__(256) void quant_pack(const float* __restrict__ x,
                                                  const float* __restrict__ w,
                                                  const float* __restrict__ Tf_in,
                                                  const float* __restrict__ Tw_in,
                                                  float* __restrict__ ws_f32,
                                                  uint8_t* __restrict__ xpad,
                                                  uint8_t* __restrict__ wfrag) {
    int blk = blockIdx.x;
    int t = threadIdx.x;
    int lane = t & 63;

    if (blk < QB_X) {
        // ---- x rows ----
        float m = fmaxf(ws_f32[WS_PART + lane], ws_f32[WS_PART + 64 + lane]);
        #pragma unroll
        for (int off = 32; off > 0; off >>= 1)
            m = fmaxf(m, __shfl_xor(m, off, 64));
        float a = 0.95f * Tf_in[0];
        float bt = 0.05f * m;
        float Tf = a + bt;
        if (blk == 0 && t == 0) ws_f32[WS_TF] = Tf;
        float scale = 127.0f / Tf;

        int b = blk >> 5, h = blk & 31;
        const float4* x4 = (const float4*)x;
        __shared__ unsigned lds[CIN * 9];   // pitch 9 dwords per ci
        #pragma unroll
        for (int k = 0; k < 2; ++k) {
            int f = t + k * 256;            // [0,512): ci = f>>3, wq = f&7
            int ci = f >> 3, wq = f & 7;
            float4 v = x4[(b * CIN + ci) * 256 + h * 8 + wq];
            unsigned pack = quantb(v.x, scale) | (quantb(v.y, scale) << 8) |
                            (quantb(v.z, scale) << 16) | (quantb(v.w, scale) << 24);
            lds[ci * 9 + wq] = pack;
        }
        __syncthreads();
        const uint8_t* ldsb = (const uint8_t*)lds;
        unsigned* orow = (unsigned*)(xpad + (((b * PH) + (h + 1)) * PW + 1) * CIN);
        #pragma unroll
        for (int k = 0; k < 2; ++k) {
            int o = t + k * 256;            // [0,512): w = o>>4, c4 = o&15
            int ww_ = o >> 4, c4 = o & 15;
            unsigned d = (unsigned)ldsb[(c4 * 4 + 0) * 36 + ww_]
                       | ((unsigned)ldsb[(c4 * 4 + 1) * 36 + ww_] << 8)
                       | ((unsigned)ldsb[(c4 * 4 + 2) * 36 + ww_] << 16)
                       | ((unsigned)ldsb[(c4 * 4 + 3) * 36 + ww_] << 24);
            orow[o] = d;
        }
    } else if (blk < QB_X + QB_W) {
        // ---- weights ----
        float m = ws_f32[WS_PART + 128 + (lane & 15)];
        #pragma unroll
        for (int off = 32; off > 0; off >>= 1)
            m = fmaxf(m, __shfl_xor(m, off, 64));
        float a = 0.95f * Tw_in[0];
        float bt = 0.05f * m;
        float Tw = a + bt;
        if (blk == QB_X && t == 0) ws_f32[WS_TW] = Tw;
        float scale = 127.0f / Tw;

        int tid = (blk - QB_X) * 256 + t;
        int idx4 = tid * 4;
        int j0 = idx4 & 15;
        int ln = (idx4 >> 4) & 63;
        int f  = idx4 >> 10;          // t9*8 + g
        int g = f & 7;
        int tap = f >> 3;
        int kh = tap / 3, kw = tap - kh * 3;
        int co = g * 16 + (ln & 15);
        int ci0 = (ln >> 4) * 16 + j0;
        unsigned pack = 0;
        #pragma unroll
        for (int c = 0; c < 4; ++c) {
            float v = w[((co * CIN + ci0 + c) * 3 + kh) * 3 + kw];
            pack |= quantb(v, scale) << (8 * c);
        }
        ((unsigned*)wfrag)[tid] = pack;
    } else {
        // ---- border zero-fill: 1056 pixels * 16 dwords = 16896 dwords ----
        int j = (blk - QB_X - QB_W) * 256 + t;
        int p = j >> 4, c4 = j & 15;
        int b = p / 132;
        int r = p - b * 132;
        int ih, iw;
        if (r < 34)      { ih = 0;          iw = r; }
        else if (r < 68) { ih = PH - 1;     iw = r - 34; }
        else if (r < 100){ ih = r - 68 + 1; iw = 0; }
        else             { ih = r - 100 + 1; iw = PW - 1; }
        ((unsigned*)xpad)[((b * PH + ih) * PW + iw) * 16 + c4] = 0u;
    }
}

// ---------- kernel 3: implicit-GEMM conv, 512 blocks (2/CU) ----------
__global__ __launch_bounds__(256, 2) void conv_mfma(const uint8_t* __restrict__ xpad,
                                                    const uint8_t* __restrict__ wfrag,
                                                    const float* __restrict__ bias,
                                                    const float* __restrict__ ws_f32,
                                                    float* __restrict__ out) {
    int blk = blockIdx.x;         // 512: nb = blk&1 (cout half), mb = blk>>1
    int nb = blk & 1;
    int mb = blk >> 1;
    int b = mb >> 5;
    int oh = mb & 31;
    int wave = threadIdx.x >> 6;
    int lane = threadIdx.x & 63;
    int mt = wave & 1;            // pixel half (16 pixels)
    int nh2 = wave >> 1;          // cout sub-half
    int row = lane & 15;
    int quad = lane >> 4;

    v4i acc[2];
    acc[0] = (v4i){0, 0, 0, 0};
    acc[1] = (v4i){0, 0, 0, 0};

    const uint8_t* xbase = xpad + (((b * PH + oh) * PW) + mt * 16 + row) * CIN + quad * 16;

    #pragma unroll
    for (int tp = 0; tp < 9; ++tp) {
        const int kh = tp / 3, kw = tp % 3;
        v4i afrag = *(const v4i*)(xbase + (kh * PW + kw) * CIN);
        #pragma unroll
        for (int nt = 0; nt < 2; ++nt) {
            int g = nb * 4 + nh2 * 2 + nt;
            v4i bfrag = *(const v4i*)(wfrag + (((tp * 8 + g) * 64) + lane) * 16);
            acc[nt] = __builtin_amdgcn_mfma_i32_16x16x64_i8(afrag, bfrag, acc[nt], 0, 0, 0);
        }
    }

    float Tf = ws_f32[WS_TF];
    float Tw = ws_f32[WS_TW];
    float s = (Tf / 127.0f) * (Tw / 127.0f);
    int ow0 = mt * 16 + quad * 4;
    #pragma unroll
    for (int nt = 0; nt < 2; ++nt) {
        int g = nb * 4 + nh2 * 2 + nt;
        int co = g * 16 + row;
        float bb = bias[co];
        float4 o;
        o.x = (float)acc[nt][0] * s + bb;
        o.y = (float)acc[nt][1] * s + bb;
        o.z = (float)acc[nt][2] * s + bb;
        o.w = (float)acc[nt][3] * s + bb;
        *(float4*)(out + (((b * COUT + co) * HH + oh) * WW) + ow0) = o;
    }
}

extern "C" void kernel_launch(void* const* d_in, const int* in_sizes, int n_in,
                              void* d_out, int out_size, void* d_ws, size_t ws_size,
                              hipStream_t stream) {
    const float* x        = (const float*)d_in[0];
    const float* weight   = (const float*)d_in[1];
    const float* bias     = (const float*)d_in[2];
    const float* T_feature = (const float*)d_in[5];
    const float* T_weight  = (const float*)d_in[6];

    float*   ws_f32 = (float*)d_ws;
    uint8_t* xpad   = (uint8_t*)d_ws + XPAD_OFF;
    uint8_t* wfrag  = (uint8_t*)d_ws + WFRAG_OFF;

    absmax_partial<<<144, 256, 0, stream>>>(x, weight, ws_f32);
    quant_pack<<<QB_X + QB_W + QB_Z, 256, 0, stream>>>(x, weight, T_feature, T_weight,
                                                       ws_f32, xpad, wfrag);
    conv_mfma<<<512, 256, 0, stream>>>(xpad, wfrag, bias, ws_f32, (float*)d_out);
}